// Round 9
// baseline (8568.797 us; speedup 1.0000x reference)
//
#include <hip/hip_runtime.h>
#include <stdint.h>

// AutoregressiveRAM: 4095 serial steps of an 8192-neuron weightless NN.
// R9 = R2 skeleton (best: 16 blocks, 8 worker waves x 64 = 512 neurons, two
// barriers, L2 table lookup, out-store-then-publish, agent-scope tagged
// mailbox) + ONE structural change: a DEDICATED POLLER WAVE (wave 8).
//   - Workers never poll. Poller lanes 0..59 each own 4 remote mailbox words
//     and sample them with a single asm batch: 4x global_load_dwordx2 sc0 sc1
//     back-to-back + s_waitcnt vmcnt(0). SOUND (vs R7): every load drains
//     inside its asm block; nothing is ever abandoned in flight.
//   - All 240 words sampled on ONE cadence clock (~950cy): detection becomes
//     a single phase draw + RTT (~1400cy) instead of the max over 240
//     independent blocking-spin phases (~cadence + RTT ~= 1800cy).
//   - Poller lane 63 writes the pos-bits word; workers self-write their own
//     16 state words to LDS (R2 style).
//
// Protocol (R2-proven, unchanged): state s -> mailbox slot[s&1], 8B word =
// (data32 lo, tag32=s+1 hi); tag travels WITH data -> self-checking; stale
// or garbage words never match the awaited tag; fuse expiry writes poison
// -> visible test failure, never silent corruption. Overwrite safety and
// replay safety proofs as in R2 (slot reuse separated by a full step + two
// barriers; mailbox memset each call; tags strictly positive).

#define BITS   8192
#define NBT    10
#define NBLK   16
#define NPB    512             // worker neurons per block (waves 0..7)
#define TPB    (NPB + 64)      // + 1 poller wave
#define SWORDS 256             // 8192 state bits / 32
#define WPB    16              // state words owned per block
#define BFUSE  1024            // poll batches per step before poisoning

__global__ void pack_kernel(const float* __restrict__ tm, uint32_t* __restrict__ packed) {
    // 8192*1024 floats -> 262144 packed u32 words. One float per thread.
    int tid = blockIdx.x * blockDim.x + threadIdx.x;
    float v = tm[tid];
    unsigned long long m = __ballot(v > 0.5f);
    int lane = tid & 63;
    if ((lane & 31) == 0) {
        packed[tid >> 5] = (lane == 0) ? (uint32_t)m : (uint32_t)(m >> 32);
    }
}

__global__ __launch_bounds__(TPB) void ram_step_kernel(
    const int* __restrict__ conn,        // [8192][10]
    const float* __restrict__ init_mem,  // [8192][16]
    const uint32_t* __restrict__ packedT,// [8192][32]
    unsigned long long* __restrict__ pairs, // [2][SWORDS] (data lo32, tag hi32)
    float* __restrict__ out,             // [length][8192]
    int length)
{
    const int b = blockIdx.x;
    const int t = threadIdx.x;
    const int lane = t & 63;

    __shared__ uint32_t st[SWORDS + 1];  // full state + pos-bits word

    if (t < NPB) {
        // ================= WORKER PATH (waves 0..7) =================
        const int n = b * NPB + t;       // this thread's neuron
        int c[NBT];
#pragma unroll
        for (int j = 0; j < NBT; ++j) c[j] = conn[n * NBT + j];

        const int gw = b * WPB + (t >> 6) * 2;  // wave's global state-word base

        // step 0: pos bits of 0 all zero -> addr 0 -> initial_memory[:,0]
        float v0 = init_mem[n << 4];
        int bit = (v0 > 0.5f) ? 1 : 0;
        unsigned long long m = __ballot(bit);
        if (lane == 0) {
            const unsigned long long tag = 1ull << 32;  // tag(state s) = s+1
            __hip_atomic_store(&pairs[gw],     tag | (uint32_t)m,
                               __ATOMIC_RELAXED, __HIP_MEMORY_SCOPE_AGENT);
            __hip_atomic_store(&pairs[gw + 1], tag | (uint32_t)(m >> 32),
                               __ATOMIC_RELAXED, __HIP_MEMORY_SCOPE_AGENT);
        }
        out[n] = v0;

        for (int i = 1; i < length; ++i) {
            // Phase X: self-write own state-(i-1) words to LDS
            if (lane == 0) {
                st[gw]     = (uint32_t)m;
                st[gw + 1] = (uint32_t)(m >> 32);
            }
            __syncthreads();             // barrier A: st (state i-1) complete

            // gather 10 bits -> 10-bit address (conn[0] is MSB)
            uint32_t addr = 0;
#pragma unroll
            for (int j = 0; j < NBT; ++j) {
                int cc = c[j];
                addr = (addr << 1) | ((st[cc >> 5] >> (cc & 31)) & 1u);
            }
            uint32_t pw = packedT[(n << 5) + (addr >> 5)];
            bit = (pw >> (addr & 31)) & 1;
            out[(size_t)i * BITS + n] = (float)bit;

            // publish state i (R2 order: after the out-store)
            m = __ballot(bit);
            if (lane == 0) {
                const unsigned long long tag = ((unsigned long long)(i + 1)) << 32;
                const int base = (i & 1) * SWORDS + gw;
                __hip_atomic_store(&pairs[base],     tag | (uint32_t)m,
                                   __ATOMIC_RELAXED, __HIP_MEMORY_SCOPE_AGENT);
                __hip_atomic_store(&pairs[base + 1], tag | (uint32_t)(m >> 32),
                                   __ATOMIC_RELAXED, __HIP_MEMORY_SCOPE_AGENT);
            }
            __syncthreads();             // barrier B: gather reads done
        }
    } else {
        // ================= POLLER PATH (wave 8) =================
        const int l = t - NPB;           // 0..63
        const bool have = (l < 60);      // lanes 0..59 own 4 remote words each
        uint32_t w0 = 0, w1 = 0, w2 = 0, w3 = 0;
        if (have) {
            int r = l * 4;
            w0 = r + 0 + ((r + 0) >= b * WPB ? WPB : 0);
            w1 = r + 1 + ((r + 1) >= b * WPB ? WPB : 0);
            w2 = r + 2 + ((r + 2) >= b * WPB ? WPB : 0);
            w3 = r + 3 + ((r + 3) >= b * WPB ? WPB : 0);
        }

        for (int i = 1; i < length; ++i) {
            if (l == 63) {
                // pos bits of step i: x[8192+j] = (i >> (3-j)) & 1, j=0..3
                st[SWORDS] = ((i >> 3) & 1) | (((i >> 2) & 1) << 1) |
                             (((i >> 1) & 1) << 2) | ((i & 1) << 3);
            }
            if (have) {
                unsigned long long* base = &pairs[((i - 1) & 1) * SWORDS];
                unsigned long long* a0 = base + w0;
                unsigned long long* a1 = base + w1;
                unsigned long long* a2 = base + w2;
                unsigned long long* a3 = base + w3;
                const uint32_t want = (uint32_t)i;
                int need = 0xF;
                for (int f = 0; f < BFUSE && need; ++f) {
                    uint64_t v0, v1, v2, v3;
                    // one batched sample of all 4 words: 4 issues + 1 drain.
                    // sound: nothing stays in flight past this block.
                    asm volatile(
                        "global_load_dwordx2 %0, %4, off sc0 sc1\n\t"
                        "global_load_dwordx2 %1, %5, off sc0 sc1\n\t"
                        "global_load_dwordx2 %2, %6, off sc0 sc1\n\t"
                        "global_load_dwordx2 %3, %7, off sc0 sc1\n\t"
                        "s_waitcnt vmcnt(0)"
                        : "=&v"(v0), "=&v"(v1), "=&v"(v2), "=&v"(v3)
                        : "v"(a0), "v"(a1), "v"(a2), "v"(a3)
                        : "memory");
                    if ((need & 1) && (uint32_t)(v0 >> 32) == want) {
                        st[w0] = (uint32_t)v0; need &= ~1;
                    }
                    if ((need & 2) && (uint32_t)(v1 >> 32) == want) {
                        st[w1] = (uint32_t)v1; need &= ~2;
                    }
                    if ((need & 4) && (uint32_t)(v2 >> 32) == want) {
                        st[w2] = (uint32_t)v2; need &= ~4;
                    }
                    if ((need & 8) && (uint32_t)(v3 >> 32) == want) {
                        st[w3] = (uint32_t)v3; need &= ~8;
                    }
                }
                if (need) {              // fuse expiry: poison -> visible fail
                    if (need & 1) st[w0] = 0xDEADBEEFu;
                    if (need & 2) st[w1] = 0xDEADBEEFu;
                    if (need & 4) st[w2] = 0xDEADBEEFu;
                    if (need & 8) st[w3] = 0xDEADBEEFu;
                }
            }
            __syncthreads();             // barrier A
            __syncthreads();             // barrier B
        }
    }
}

extern "C" void kernel_launch(void* const* d_in, const int* in_sizes, int n_in,
                              void* d_out, int out_size, void* d_ws, size_t ws_size,
                              hipStream_t stream) {
    const float* tm = (const float*)d_in[0];     // transition_memory [8192][1024]
    const float* im = (const float*)d_in[1];     // initial_memory    [8192][16]
    const int*   tc = (const int*)d_in[2];       // transition_connections [8192][10]
    // d_in[3] (initial_connections) is provably unused: pos_bits(0)==0 -> addr 0.
    const int length = out_size / BITS;

    uint32_t* packed = (uint32_t*)d_ws;                                   // 1 MB
    unsigned long long* pairs =
        (unsigned long long*)((char*)d_ws + (1 << 20));                   // 4 KB

    // Clean mailbox every call/replay (graph-capturable memset node).
    hipMemsetAsync(pairs, 0, 2 * SWORDS * sizeof(unsigned long long), stream);

    // Pack transition RAM to bits: 8192*1024 floats, 1 thread each.
    pack_kernel<<<dim3((BITS * 1024) / 256), dim3(256), 0, stream>>>(tm, packed);

    // Persistent recurrence kernel: 16 blocks (always co-resident on 256 CUs).
    ram_step_kernel<<<dim3(NBLK), dim3(TPB), 0, stream>>>(
        tc, im, packed, pairs, (float*)d_out, length);
}

// Round 10
// 8140.665 us; speedup vs baseline: 1.0526x; 1.0526x over previous
//
#include <hip/hip_runtime.h>
#include <stdint.h>

// AutoregressiveRAM: 4095 serial steps of an 8192-neuron weightless NN.
// R10 = R2-EXACT champion skeleton (16 blocks x 512 thr, two barriers,
// single-buffer LDS state, L2 table lookup, out-store-then-publish,
// agent-scope tagged mailbox) + ONE change: PHASE-LOCKED POLL SAMPLING.
//   All 240 polling threads issue their spin loads only at global multiples
//   of P ref-clock ticks (s_memrealtime = chip-wide constant clock). This
//   collapses detection from max-over-240-random-phases (~cadence+RTT
//   ~1800cy) to one shared phase draw + RTT (~1350cy). P is self-calibrated
//   (s_memtime/s_memrealtime ratio, ~8us once, clamped [4,64] ticks) so a
//   wrong clock-frequency assumption degrades to ~plain spinning, never
//   explodes. Guard loops are iteration-capped; fuse expiry poisons ->
//   visible test failure, never silent corruption.
//
// Protocol (R2-proven, unchanged): state s -> mailbox slot[s&1], 8B word =
// (data32 lo, tag32=s+1 hi); tag travels WITH data -> self-checking; stale
// words never match the awaited tag. Overwrite safety: slot reuse at step
// i+2 is gated by iter-(i+1) poll success + barriers (R2 proof). Replay-
// safe: mailbox memset each call; tags strictly positive.

#define BITS   8192
#define NBT    10
#define NBLK   16
#define TPB    512
#define NPB    (BITS / NBLK)   // 512 neurons per block (1 per thread)
#define SWORDS 256             // 8192 state bits / 32
#define WPB    (NPB / 32)      // 16 state words owned per block
#define FUSE   (1 << 12)       // bounded samples per step; expiry -> poison

__global__ void pack_kernel(const float* __restrict__ tm, uint32_t* __restrict__ packed) {
    // 8192*1024 floats -> 262144 packed u32 words. One float per thread.
    int tid = blockIdx.x * blockDim.x + threadIdx.x;
    float v = tm[tid];
    unsigned long long m = __ballot(v > 0.5f);
    int lane = tid & 63;
    if ((lane & 31) == 0) {
        packed[tid >> 5] = (lane == 0) ? (uint32_t)m : (uint32_t)(m >> 32);
    }
}

// Chip-wide constant-rate clock (REFCLK). SGPR result; wave-uniform.
__device__ __forceinline__ uint64_t rtc() {
    uint64_t v;
    asm volatile("s_memrealtime %0\n\ts_waitcnt lgkmcnt(0)" : "=s"(v));
    return v;
}
// Shader-clock counter (for one-time calibration only).
__device__ __forceinline__ uint64_t stc() {
    uint64_t v;
    asm volatile("s_memtime %0\n\ts_waitcnt lgkmcnt(0)" : "=s"(v));
    return v;
}

__global__ __launch_bounds__(TPB) void ram_step_kernel(
    const int* __restrict__ conn,        // [8192][10]
    const float* __restrict__ init_mem,  // [8192][16]
    const uint32_t* __restrict__ packedT,// [8192][32]
    unsigned long long* __restrict__ pairs, // [2][SWORDS] (data lo32, tag hi32)
    float* __restrict__ out,             // [length][8192]
    int length)
{
    const int b = blockIdx.x;
    const int t = threadIdx.x;
    const int lane = t & 63;
    const int n = b * NPB + t;           // this thread's neuron

    __shared__ uint32_t st[SWORDS + 1];  // full state + pos-bits word

    // ---- one-time REFCLK calibration (~8us, off the recurrence path) ----
    // ratio = shader cycles per ref tick; P = ticks per ~1000 shader cycles
    // (sample period ~= spin-load RTT). Clamped so garbage readings degrade
    // to near-plain spinning rather than long stalls.
    uint32_t Ps;
    {
        uint64_t ts0 = stc(), rr0 = rtc();
#pragma unroll 1
        for (int k = 0; k < 128; ++k) __builtin_amdgcn_s_sleep(2);
        uint64_t dt = stc() - ts0;
        uint64_t dr = rtc() - rr0;
        uint32_t ratio = dr ? (uint32_t)(dt / dr) : 64;
        if (ratio == 0) ratio = 1;
        Ps = 1000u / ratio;
        if (Ps < 4) Ps = 4; else if (Ps > 64) Ps = 64;
    }

    // Connections are static: keep in registers for the whole run.
    int c[NBT];
#pragma unroll
    for (int j = 0; j < NBT; ++j) c[j] = conn[n * NBT + j];

    // ---- step 0: pos bits of 0 are all zero -> addr 0 -> initial_memory[:,0]
    float v0 = init_mem[n << 4];
    out[n] = v0;
    int bit = (v0 > 0.5f) ? 1 : 0;
    unsigned long long m = __ballot(bit);
    const int gw = b * WPB + (t >> 6) * 2;  // this wave's global state-word base
    if (lane == 0) {
        const unsigned long long tag = 1ull << 32;  // tag(step s) = s+1
        __hip_atomic_store(&pairs[gw],     tag | (uint32_t)m,
                           __ATOMIC_RELAXED, __HIP_MEMORY_SCOPE_AGENT);
        __hip_atomic_store(&pairs[gw + 1], tag | (uint32_t)(m >> 32),
                           __ATOMIC_RELAXED, __HIP_MEMORY_SCOPE_AGENT);
        st[gw]     = (uint32_t)m;        // own slice goes straight to LDS
        st[gw + 1] = (uint32_t)(m >> 32);
    }

    for (int i = 1; i < length; ++i) {
        const int parity = (i - 1) & 1;
        const uint32_t want = (uint32_t)i;          // waiting for tag of step i-1

        if (t == 0) {
            // pos bits of step i: x[8192+j] = (i >> (3-j)) & 1
            st[SWORDS] = ((i >> 3) & 1) | (((i >> 2) & 1) << 1) |
                         (((i >> 1) & 1) << 2) | ((i & 1) << 3);
        }
        if (t < SWORDS && (t >> 4) != b) {          // poll everyone else's words
            unsigned long long* p = &pairs[parity * SWORDS + t];
            // immediate first sample: zero added latency if already visible
            unsigned long long pv =
                __hip_atomic_load(p, __ATOMIC_RELAXED, __HIP_MEMORY_SCOPE_AGENT);
            if ((uint32_t)(pv >> 32) != want) {
                // phase-locked mode: sample only at global ticks k*Ps
                uint64_t rt = rtc();
                uint64_t nxt = rt / Ps * Ps;        // one div per step entry
                int fuse = 0;
                do {
                    rt = rtc();
                    do { nxt += Ps; } while (nxt <= rt);   // stay on global grid
                    int g = 0;
                    while (rt < nxt && ++g < 100) {        // capped tick wait
                        __builtin_amdgcn_s_sleep(1);
                        rt = rtc();
                    }
                    pv = __hip_atomic_load(p, __ATOMIC_RELAXED,
                                           __HIP_MEMORY_SCOPE_AGENT);
                } while ((uint32_t)(pv >> 32) != want && ++fuse < FUSE);
            }
            st[t] = (uint32_t)pv;
        }
        __syncthreads();

        // gather 10 bits -> 10-bit address (conn[0] is MSB)
        uint32_t addr = 0;
#pragma unroll
        for (int j = 0; j < NBT; ++j) {
            int cc = c[j];
            uint32_t w = st[cc >> 5];
            addr = (addr << 1) | ((w >> (cc & 31)) & 1u);
        }
        uint32_t pw = packedT[(n << 5) + (addr >> 5)];
        bit = (pw >> (addr & 31)) & 1;
        out[(size_t)i * BITS + n] = (float)bit;

        // publish own slice for step i (R2 order: after the out-store)
        m = __ballot(bit);
        if (lane == 0) {
            const unsigned long long tag = ((unsigned long long)(i + 1)) << 32;
            const int base = (i & 1) * SWORDS + gw;
            __hip_atomic_store(&pairs[base],     tag | (uint32_t)m,
                               __ATOMIC_RELAXED, __HIP_MEMORY_SCOPE_AGENT);
            __hip_atomic_store(&pairs[base + 1], tag | (uint32_t)(m >> 32),
                               __ATOMIC_RELAXED, __HIP_MEMORY_SCOPE_AGENT);
        }
        __syncthreads();                 // everyone done reading step i-1 state
        if (lane == 0) {                 // now safe to refresh own LDS words
            st[gw]     = (uint32_t)m;
            st[gw + 1] = (uint32_t)(m >> 32);
        }
    }
}

extern "C" void kernel_launch(void* const* d_in, const int* in_sizes, int n_in,
                              void* d_out, int out_size, void* d_ws, size_t ws_size,
                              hipStream_t stream) {
    const float* tm = (const float*)d_in[0];     // transition_memory [8192][1024]
    const float* im = (const float*)d_in[1];     // initial_memory    [8192][16]
    const int*   tc = (const int*)d_in[2];       // transition_connections [8192][10]
    // d_in[3] (initial_connections) is provably unused: pos_bits(0)==0 -> addr 0.
    const int length = out_size / BITS;

    uint32_t* packed = (uint32_t*)d_ws;                                   // 1 MB
    unsigned long long* pairs =
        (unsigned long long*)((char*)d_ws + (1 << 20));                   // 4 KB

    // Clean mailbox every call/replay (graph-capturable memset node).
    hipMemsetAsync(pairs, 0, 2 * SWORDS * sizeof(unsigned long long), stream);

    // Pack transition RAM to bits: 8192*1024 floats, 1 thread each.
    pack_kernel<<<dim3((BITS * 1024) / 256), dim3(256), 0, stream>>>(tm, packed);

    // Persistent recurrence kernel: 16 blocks (always co-resident on 256 CUs).
    ram_step_kernel<<<dim3(NBLK), dim3(TPB), 0, stream>>>(
        tc, im, packed, pairs, (float*)d_out, length);
}

// Round 11
// 5882.090 us; speedup vs baseline: 1.4568x; 1.3840x over previous
//
#include <hip/hip_runtime.h>
#include <stdint.h>

// AutoregressiveRAM: 4095 serial steps of an 8192-neuron weightless NN.
// R11 = R2-EXACT champion skeleton (16 blocks x 512 thr, two barriers,
// single-buffer LDS state, L2 table lookup, out-store-then-publish,
// per-thread independent blocking spin) with ONE substitution:
//   mailbox ops hand-encoded as plain `sc0 sc1` global load/store
//   (bypass L1+L2, served at the L3/fabric coherence point, L3-CACHEABLE)
//   instead of __hip_atomic_* AGENT builtins, which may carry `nt`
//   (L3-bypass -> HBM-class ~900cy RTT) or conservative cache maintenance.
//   Structure of the spin is byte-identical to R2: one blocking load +
//   vmcnt(0) per iteration, per-thread independent channels.
//
// Soundness: all asm loads drain (vmcnt(0)) inside their asm block - nothing
// is ever left in flight targeting compiler-managed registers (R7 lesson).
// Interop precedent: R9 PASSED with sc0 sc1 poll loads; stores here write
// through to the same coherence point the loads read.
//
// Protocol (R2-proven): state s -> mailbox slot[s&1], 8B word = (data32 lo,
// tag32=s+1 hi); tag travels WITH data -> self-checking; stale/garbage words
// never match the awaited tag; fuse expiry -> poison -> visible test failure,
// never silent corruption. Overwrite safety: slot reuse at step i+2 is gated
// by iter-(i+1) poll success + two barriers (R2 proof). Replay-safe: mailbox
// memset each call; tags strictly positive.

#define BITS   8192
#define NBT    10
#define NBLK   16
#define TPB    512
#define NPB    (BITS / NBLK)   // 512 neurons per block (1 per thread)
#define SWORDS 256             // 8192 state bits / 32
#define WPB    (NPB / 32)      // 16 state words owned per block
#define FUSE   (1 << 14)       // bounded spin; expiry -> visible failure

__global__ void pack_kernel(const float* __restrict__ tm, uint32_t* __restrict__ packed) {
    // 8192*1024 floats -> 262144 packed u32 words. One float per thread.
    int tid = blockIdx.x * blockDim.x + threadIdx.x;
    float v = tm[tid];
    unsigned long long m = __ballot(v > 0.5f);
    int lane = tid & 63;
    if ((lane & 31) == 0) {
        packed[tid >> 5] = (lane == 0) ? (uint32_t)m : (uint32_t)(m >> 32);
    }
}

// Blocking mailbox sample: bypass L1+L2, served by L3/fabric coherence point,
// L3-cacheable (no nt). Fully drained inside the asm block (sound).
__device__ __forceinline__ uint64_t spin_ld(const uint64_t* p) {
    uint64_t v;
    asm volatile("global_load_dwordx2 %0, %1, off sc0 sc1\n\t"
                 "s_waitcnt vmcnt(0)"
                 : "=v"(v) : "v"(p) : "memory");
    return v;
}
// Publish: write-through L1+L2 to the L3 coherence point; 8B atom keeps the
// tag traveling with its data.
__device__ __forceinline__ void spin_st(uint64_t* p, uint64_t v) {
    asm volatile("global_store_dwordx2 %0, %1, off sc0 sc1"
                 : : "v"(p), "v"(v) : "memory");
}

__global__ __launch_bounds__(TPB) void ram_step_kernel(
    const int* __restrict__ conn,        // [8192][10]
    const float* __restrict__ init_mem,  // [8192][16]
    const uint32_t* __restrict__ packedT,// [8192][32]
    uint64_t* __restrict__ pairs,        // [2][SWORDS] (data lo32, tag hi32)
    float* __restrict__ out,             // [length][8192]
    int length)
{
    const int b = blockIdx.x;
    const int t = threadIdx.x;
    const int lane = t & 63;
    const int n = b * NPB + t;           // this thread's neuron

    __shared__ uint32_t st[SWORDS + 1];  // full state + pos-bits word

    // Connections are static: keep in registers for the whole run.
    int c[NBT];
#pragma unroll
    for (int j = 0; j < NBT; ++j) c[j] = conn[n * NBT + j];

    // ---- step 0: pos bits of 0 are all zero -> addr 0 -> initial_memory[:,0]
    float v0 = init_mem[n << 4];
    out[n] = v0;
    int bit = (v0 > 0.5f) ? 1 : 0;
    unsigned long long m = __ballot(bit);
    const int gw = b * WPB + (t >> 6) * 2;  // this wave's global state-word base
    if (lane == 0) {
        const uint64_t tag = 1ull << 32;    // tag(step s) = s+1
        spin_st(&pairs[gw],     tag | (uint32_t)m);
        spin_st(&pairs[gw + 1], tag | (uint32_t)(m >> 32));
        st[gw]     = (uint32_t)m;        // own slice goes straight to LDS
        st[gw + 1] = (uint32_t)(m >> 32);
    }

    for (int i = 1; i < length; ++i) {
        const int parity = (i - 1) & 1;
        const uint32_t want = (uint32_t)i;          // waiting for tag of step i-1

        if (t == 0) {
            // pos bits of step i: x[8192+j] = (i >> (3-j)) & 1
            st[SWORDS] = ((i >> 3) & 1) | (((i >> 2) & 1) << 1) |
                         (((i >> 1) & 1) << 2) | ((i & 1) << 3);
        }
        if (t < SWORDS && (t >> 4) != b) {          // poll everyone else's words
            uint64_t* p = &pairs[parity * SWORDS + t];
            uint64_t pv;
            int fuse = 0;
            do {
                pv = spin_ld(p);
            } while ((uint32_t)(pv >> 32) != want && ++fuse < FUSE);
            if ((uint32_t)(pv >> 32) != want) pv = 0xDEADBEEFull;  // poison
            st[t] = (uint32_t)pv;
        }
        __syncthreads();

        // gather 10 bits -> 10-bit address (conn[0] is MSB)
        uint32_t addr = 0;
#pragma unroll
        for (int j = 0; j < NBT; ++j) {
            int cc = c[j];
            uint32_t w = st[cc >> 5];
            addr = (addr << 1) | ((w >> (cc & 31)) & 1u);
        }
        uint32_t pw = packedT[(n << 5) + (addr >> 5)];
        bit = (pw >> (addr & 31)) & 1;
        out[(size_t)i * BITS + n] = (float)bit;

        // publish own slice for step i (R2 order: after the out-store)
        m = __ballot(bit);
        if (lane == 0) {
            const uint64_t tag = ((uint64_t)(i + 1)) << 32;
            const int base = (i & 1) * SWORDS + gw;
            spin_st(&pairs[base],     tag | (uint32_t)m);
            spin_st(&pairs[base + 1], tag | (uint32_t)(m >> 32));
        }
        __syncthreads();                 // everyone done reading step i-1 state
        if (lane == 0) {                 // now safe to refresh own LDS words
            st[gw]     = (uint32_t)m;
            st[gw + 1] = (uint32_t)(m >> 32);
        }
    }
}

extern "C" void kernel_launch(void* const* d_in, const int* in_sizes, int n_in,
                              void* d_out, int out_size, void* d_ws, size_t ws_size,
                              hipStream_t stream) {
    const float* tm = (const float*)d_in[0];     // transition_memory [8192][1024]
    const float* im = (const float*)d_in[1];     // initial_memory    [8192][16]
    const int*   tc = (const int*)d_in[2];       // transition_connections [8192][10]
    // d_in[3] (initial_connections) is provably unused: pos_bits(0)==0 -> addr 0.
    const int length = out_size / BITS;

    uint32_t* packed = (uint32_t*)d_ws;                              // 1 MB
    uint64_t* pairs  = (uint64_t*)((char*)d_ws + (1 << 20));         // 4 KB

    // Clean mailbox every call/replay (graph-capturable memset node).
    hipMemsetAsync(pairs, 0, 2 * SWORDS * sizeof(uint64_t), stream);

    // Pack transition RAM to bits: 8192*1024 floats, 1 thread each.
    pack_kernel<<<dim3((BITS * 1024) / 256), dim3(256), 0, stream>>>(tm, packed);

    // Persistent recurrence kernel: 16 blocks (always co-resident on 256 CUs).
    ram_step_kernel<<<dim3(NBLK), dim3(TPB), 0, stream>>>(
        tc, im, packed, pairs, (float*)d_out, length);
}